// Round 3
// baseline (136.292 us; speedup 1.0000x reference)
//
#include <hip/hip_runtime.h>

// Shapes: x [n=32, c=32, s=1, h=48, w=48]; hw = 2304; c*s = 32.
// out[n,i,d] = gamma * f_d(q_i) + x   where f_d(t) = sum_j e^{t k_j} v[j,d] / sum_j e^{t k_j}
// (energy is rank-1: q_i * k_j). f is smooth in one variable -> 64-node
// Chebyshev barycentric interpolation on the exact per-batch q-range.
//
// Workspace (small, 547 KB): pool + pool-min/max partials + node values F.
// v (9.4 MB) is staged in d_out: prep writes it, fnode reads it, eval
// overwrites all of d_out with the final result (same-stream ordering).
#define NB 32
#define CC 32
#define HW 2304
#define RN 64                     // Chebyshev nodes per batch
#define LOG2E 1.4426950408889634f
#define PI_F  3.14159265358979323846f

// Workspace layout (float offsets). Total = 139840 floats = 547 KB.
#define OFF_POOL 0u          // pool[n][hw]      73728
#define OFF_PART 73728u      // min/max partials, 288 blocks * 2 = 576
#define OFF_F    74304u      // F[n][r][32]      65536

__device__ __forceinline__ float frcp(float v) { return __builtin_amdgcn_rcpf(v); }

// ---------------------------------------------------------------------------
// Kernel 1: pool = mean_c + max_c (store); v = Wv@x + bv (1x1 conv) -> vout;
// per-block pool min/max partials. One pass over x.
// grid (9, 32), block 256: thread = one spatial position p.
// ---------------------------------------------------------------------------
__global__ __launch_bounds__(256) void prep_kernel(
    const float* __restrict__ x,
    const float* __restrict__ Wv, const float* __restrict__ bv,
    float* __restrict__ vout,      // = d_out used as scratch for v[n][c][hw]
    float* __restrict__ ws)
{
    __shared__ float smin[256], smax[256];
    const int tid = threadIdx.x;
    const int n   = blockIdx.y;
    const int p   = blockIdx.x * 256 + tid;

    const float* xb = x + (size_t)n * (CC * HW) + p;
    float xx[CC];
    float sum = 0.f, mx = -3.0e38f;
#pragma unroll
    for (int c = 0; c < CC; ++c) {
        float v = xb[(size_t)c * HW];   // coalesced across threads
        xx[c] = v;
        sum += v;
        mx = fmaxf(mx, v);
    }
    const float pool = sum * (1.0f / CC) + mx;
    ws[OFF_POOL + n * HW + p] = pool;

    // channel-mix: Wv indices are uniform -> scalar loads, no LDS needed
    float* vb = vout + (size_t)n * (CC * HW) + p;
#pragma unroll 8
    for (int o = 0; o < CC; ++o) {
        float acc = bv[o];
#pragma unroll
        for (int c = 0; c < CC; ++c) acc = fmaf(Wv[o * CC + c], xx[c], acc);
        vb[(size_t)o * HW] = acc;       // coalesced across threads
    }

    // block-level pool min/max
    smin[tid] = pool; smax[tid] = pool;
    __syncthreads();
    for (int s = 128; s > 0; s >>= 1) {
        if (tid < s) {
            smin[tid] = fminf(smin[tid], smin[tid + s]);
            smax[tid] = fmaxf(smax[tid], smax[tid + s]);
        }
        __syncthreads();
    }
    if (tid == 0) {
        const int b = n * gridDim.x + blockIdx.x;
        ws[OFF_PART + 2 * b]     = smin[0];
        ws[OFF_PART + 2 * b + 1] = smax[0];
    }
}

// ---------------------------------------------------------------------------
// Kernel 2: node values F[n][r][d] = sum_j e^{t_r k_j - m_r} v[j,d] / Z.
// k_j computed on the fly from pool. v read from vscratch (= d_out).
// grid (RN, 32), block 256: 8 threads per j-group (each owns 4 d's).
// v_r[j,d] == v flat at j*32+d (torch .view reshape identity).
// ---------------------------------------------------------------------------
__global__ __launch_bounds__(256) void fnode_kernel(
    const float* __restrict__ Wq, const float* __restrict__ bq,
    const float* __restrict__ Wk, const float* __restrict__ bk,
    const float* __restrict__ vscratch,
    float* __restrict__ ws)
{
    __shared__ float sk[HW];
    __shared__ float sG[256 * 4];
    __shared__ float sZ[256];
    __shared__ float sh[2];
    const int tid = threadIdx.x;
    const int r   = blockIdx.x;
    const int n   = blockIdx.y;

    const float Wk0 = Wk[0], bk0 = bk[0];
    const float* pb = ws + OFF_POOL + n * HW;
    for (int idx = tid; idx < HW; idx += 256)
        sk[idx] = fmaf(Wk0, pb[idx], bk0);

    if (tid == 0) {
        float pmin = 3.0e38f, pmax = -3.0e38f;
        for (int b = 0; b < 9; ++b) {
            pmin = fminf(pmin, ws[OFF_PART + 2 * (n * 9 + b)]);
            pmax = fmaxf(pmax, ws[OFF_PART + 2 * (n * 9 + b) + 1]);
        }
        const float q1 = fmaf(Wq[0], pmin, bq[0]);
        const float q2 = fmaf(Wq[0], pmax, bq[0]);
        const float qlo = fminf(q1, q2), qhi = fmaxf(q1, q2);
        const float k1 = fmaf(Wk0, pmin, bk0);
        const float k2 = fmaf(Wk0, pmax, bk0);
        const float klo = fminf(k1, k2), khi = fmaxf(k1, k2);
        const float mid  = 0.5f * (qlo + qhi);
        const float half = fmaxf(0.5f * (qhi - qlo), 1e-6f);
        const float t = fmaf(half, cosf(PI_F * (float)r / (float)(RN - 1)), mid);
        const float m = fmaxf(t * klo, t * khi);   // == max_j t*k_j (k range exact)
        sh[0] = t * LOG2E;
        sh[1] = m * LOG2E;
    }
    __syncthreads();
    const float tl = sh[0];
    const float ml = sh[1];

    const int dg = tid & 7;        // 4-wide d group
    const int jg = tid >> 3;       // 32 j-groups of 72 consecutive j
    const float* vb = vscratch + (size_t)n * (CC * HW) + dg * 4;
    float a0 = 0.f, a1 = 0.f, a2 = 0.f, a3 = 0.f, az = 0.f;
    const int jbase = jg * 72;
    for (int jj = 0; jj < 72; ++jj) {
        const int j = jbase + jj;
        const float e = exp2f(fmaf(tl, sk[j], -ml));   // exponent <= 0 -> Z >= 1
        const float4 v4 = *(const float4*)(vb + (size_t)j * 32);
        a0 = fmaf(e, v4.x, a0);
        a1 = fmaf(e, v4.y, a1);
        a2 = fmaf(e, v4.z, a2);
        a3 = fmaf(e, v4.w, a3);
        az += e;
    }
    sG[tid * 4 + 0] = a0;
    sG[tid * 4 + 1] = a1;
    sG[tid * 4 + 2] = a2;
    sG[tid * 4 + 3] = a3;
    sZ[tid] = az;
    __syncthreads();
    if (tid < 32) {
        const int dgl = tid >> 2, dd = tid & 3;   // dgl*4+dd == tid == d
        float g = 0.f, z = 0.f;
        for (int j2 = 0; j2 < 32; ++j2) {
            g += sG[(j2 * 8 + dgl) * 4 + dd];
            z += sZ[j2 * 8];                 // all 8 threads of a j-group hold same az
        }
        ws[OFF_F + ((size_t)n * RN + r) * 32 + tid] = g / z;
    }
}

// ---------------------------------------------------------------------------
// Kernel 3: barycentric evaluation at each q_i + residual epilogue.
// Overwrites ALL of d_out (which held v scratch).
// grid (72, 32), block 256: 8 threads per i (4 d's each) -> coalesced float4 IO.
// ---------------------------------------------------------------------------
__global__ __launch_bounds__(256) void eval_kernel(
    const float* __restrict__ x,
    const float* __restrict__ Wq, const float* __restrict__ bq,
    const float* __restrict__ gamma,
    const float* __restrict__ ws,
    float* __restrict__ out)
{
    __shared__ __align__(16) float sF[RN * 32];
    __shared__ float stn[RN];
    __shared__ float sstat[2];
    const int tid = threadIdx.x;
    const int n   = blockIdx.y;

    if (tid == 0) {
        float pmin = 3.0e38f, pmax = -3.0e38f;
        for (int b = 0; b < 9; ++b) {
            pmin = fminf(pmin, ws[OFF_PART + 2 * (n * 9 + b)]);
            pmax = fmaxf(pmax, ws[OFF_PART + 2 * (n * 9 + b) + 1]);
        }
        sstat[0] = pmin; sstat[1] = pmax;
    }
    const float* Fb = ws + OFF_F + (size_t)n * RN * 32;
    for (int idx = tid; idx < RN * 32; idx += 256) sF[idx] = Fb[idx];
    __syncthreads();
    if (tid < RN) {
        const float pmin = sstat[0], pmax = sstat[1];
        const float q1 = fmaf(Wq[0], pmin, bq[0]);
        const float q2 = fmaf(Wq[0], pmax, bq[0]);
        const float qlo = fminf(q1, q2), qhi = fmaxf(q1, q2);
        const float mid  = 0.5f * (qlo + qhi);
        const float half = fmaxf(0.5f * (qhi - qlo), 1e-6f);
        stn[tid] = fmaf(half, cosf(PI_F * (float)tid / (float)(RN - 1)), mid);
    }
    __syncthreads();

    const int il = tid >> 3;                 // 32 i's per block
    const int dg = tid & 7;                  // 4-wide d group
    const int i  = blockIdx.x * 32 + il;
    const float t = fmaf(Wq[0], ws[OFF_POOL + n * HW + i], bq[0]);  // q_i

    // Barycentric Lagrange, Chebyshev-2 weights (-1)^r * (1/2 at ends).
    float n0 = 0.f, n1 = 0.f, n2 = 0.f, n3 = 0.f, den = 0.f;
    float sgn = 1.0f;
#pragma unroll 8
    for (int r = 0; r < RN; ++r) {
        float d = t - stn[r];
        if (fabsf(d) < 1e-20f) d = 1e-20f;   // node-hit guard (weight dominates -> F_r)
        const float lam = (r == 0 || r == RN - 1) ? 0.5f : 1.0f;
        const float w = sgn * lam * frcp(d);
        sgn = -sgn;
        den += w;
        const float4 f4 = *(const float4*)(&sF[r * 32 + dg * 4]);
        n0 = fmaf(w, f4.x, n0);
        n1 = fmaf(w, f4.y, n1);
        n2 = fmaf(w, f4.z, n2);
        n3 = fmaf(w, f4.w, n3);
    }
    const float invden = frcp(den);
    const float g = gamma[0];
    const int c_out = i / 72;
    const int p_out = (i - c_out * 72) * 32 + dg * 4;
    const size_t base = (size_t)n * (CC * HW) + (size_t)c_out * HW + p_out;
    const float4 xv = *(const float4*)(x + base);
    float4 o;
    o.x = fmaf(g, n0 * invden, xv.x);
    o.y = fmaf(g, n1 * invden, xv.y);
    o.z = fmaf(g, n2 * invden, xv.z);
    o.w = fmaf(g, n3 * invden, xv.w);
    *(float4*)(out + base) = o;
}

extern "C" void kernel_launch(void* const* d_in, const int* in_sizes, int n_in,
                              void* d_out, int out_size, void* d_ws, size_t ws_size,
                              hipStream_t stream) {
    const float* x     = (const float*)d_in[0];
    const float* Wq    = (const float*)d_in[1];
    const float* bq    = (const float*)d_in[2];
    const float* Wk    = (const float*)d_in[3];
    const float* bk    = (const float*)d_in[4];
    const float* Wv    = (const float*)d_in[5];
    const float* bv    = (const float*)d_in[6];
    const float* gamma = (const float*)d_in[7];
    float* out = (float*)d_out;
    float* ws  = (float*)d_ws;   // needs only 547 KB

    // v is staged in d_out (overwritten by eval with the final result).
    prep_kernel<<<dim3(9, NB), 256, 0, stream>>>(x, Wv, bv, out, ws);
    fnode_kernel<<<dim3(RN, NB), 256, 0, stream>>>(Wq, bq, Wk, bk, out, ws);
    eval_kernel<<<dim3(72, NB), 256, 0, stream>>>(x, Wq, bq, gamma, ws, out);
}